// Round 5
// baseline (418.322 us; speedup 1.0000x reference)
//
#include <hip/hip_runtime.h>
#include <cstdint>
#include <cstddef>

// VarAttention: B=4, N=96, P=64, C=1024, H=16, hd=64. tokens = 24576.
// Buffers are FP32 (reference dtype). Internal compute: bf16 MFMA, fp32 accum.
#define PPP  64
#define CC   1024

typedef __attribute__((ext_vector_type(8))) short short8;
typedef __attribute__((ext_vector_type(4))) float floatx4;
typedef __attribute__((ext_vector_type(4))) unsigned short ushort4v;

__device__ inline float bf2f(unsigned short u) {
  union { unsigned int i; float f; } v; v.i = ((unsigned int)u) << 16; return v.f;
}
__device__ inline unsigned short f2bf(float f) {
  union { float f; unsigned int i; } v; v.f = f;
  unsigned int x = v.i;
  unsigned int r = (x + 0x7fffu + ((x >> 16) & 1u)) >> 16;  // RNE
  return (unsigned short)r;
}

// global->LDS direct DMA, 16B/lane; LDS dest = wave-uniform base + lane*16.
#define GLD16(gp, lp)                                                          \
  __builtin_amdgcn_global_load_lds(                                            \
      (const __attribute__((address_space(1))) void*)(gp),                     \
      (__attribute__((address_space(3))) void*)(lp), 16, 0, 0)

// ---------------------------------------------------------------------------
// Fused convert + mean-pool: one pass over x (96 MB fp32).
// ---------------------------------------------------------------------------
__global__ __launch_bounds__(256) void conv_mean(
    const float* __restrict__ x, unsigned short* __restrict__ xbf,
    unsigned short* __restrict__ xm) {
  int bn = blockIdx.x;
  int c4 = threadIdx.x * 4;
  const float* xp = x + (size_t)bn * (PPP * CC) + c4;
  unsigned short* xo = xbf + (size_t)bn * (PPP * CC) + c4;
  float4 s = {0.f, 0.f, 0.f, 0.f};
#pragma unroll 8
  for (int p = 0; p < PPP; ++p) {
    float4 v = *(const float4*)&xp[(size_t)p * CC];
    s.x += v.x; s.y += v.y; s.z += v.z; s.w += v.w;
    ushort4v pk;
    pk.x = f2bf(v.x); pk.y = f2bf(v.y); pk.z = f2bf(v.z); pk.w = f2bf(v.w);
    *(ushort4v*)&xo[(size_t)p * CC] = pk;
  }
  ushort4v pm;
  pm.x = f2bf(s.x * (1.0f / PPP)); pm.y = f2bf(s.y * (1.0f / PPP));
  pm.z = f2bf(s.z * (1.0f / PPP)); pm.w = f2bf(s.w * (1.0f / PPP));
  *(ushort4v*)&xm[(size_t)bn * CC + c4] = pm;
}

// ---------------------------------------------------------------------------
// Convert+transpose: dst_bf16[c][r] = src_f32[r][c]. Grid (Cc/32, R/32), 256.
// ---------------------------------------------------------------------------
__global__ __launch_bounds__(256) void transpose_f32_bf16(
    const float* __restrict__ src, unsigned short* __restrict__ dst,
    int R, int Cc, int src_stride) {
  __shared__ unsigned short tile[32][33];
  int tc = blockIdx.x * 32, tr = blockIdx.y * 32;
  int tx = threadIdx.x & 31, ty = threadIdx.x >> 5;  // 32 x 8
  for (int yy = ty; yy < 32; yy += 8)
    tile[yy][tx] = f2bf(src[(size_t)(tr + yy) * src_stride + tc + tx]);
  __syncthreads();
  for (int yy = ty; yy < 32; yy += 8)
    dst[(size_t)(tc + yy) * R + tr + tx] = tile[tx][yy];
}

// ---------------------------------------------------------------------------
// Small-M MFMA GEMM (m97 structure) kept for the qk projection only.
// ---------------------------------------------------------------------------
template <bool F32OUT, bool SWIZ>
__global__ __launch_bounds__(256) void gemm_bt(
    const unsigned short* __restrict__ A, const unsigned short* __restrict__ BT,
    void* __restrict__ Cout, const float* __restrict__ bias,
    int M, int N, int K, int nbx) {
  __shared__ unsigned short As[128 * 32];
  __shared__ unsigned short Bs[128 * 32];

  int bx, by;
  {
    int bid = blockIdx.x;
    if (SWIZ) {
      bx = (bid >> 3) & 7;
      by = (bid & 7) * (gridDim.x >> 6) + (bid >> 6);
    } else {
      bx = bid % nbx;
      by = bid / nbx;
    }
  }
  const int rowBase = by * 128;
  const int colBase = bx * 128;
  const int t = threadIdx.x;
  const int wave = t >> 6, lane = t & 63;
  const int qr = wave >> 1, qc = wave & 1;
  const int m16 = lane & 15, quad = lane >> 4;

  floatx4 acc[4][4];
#pragma unroll
  for (int i = 0; i < 4; ++i)
#pragma unroll
    for (int j = 0; j < 4; ++j) {
      acc[i][j][0] = 0.f; acc[i][j][1] = 0.f; acc[i][j][2] = 0.f; acc[i][j][3] = 0.f;
    }

  for (int k0 = 0; k0 < K; k0 += 32) {
    __syncthreads();
#pragma unroll
    for (int u = 0; u < 2; ++u) {
      int ch = (u * 4 + wave) * 64 + lane;      // 0..511
      int row = ch >> 2, c8 = (ch & 3) << 3;    // 16B chunks of a 32-wide k-row
      GLD16(&A [(size_t)(rowBase + row) * K + k0 + c8], &As[ch * 8]);
      GLD16(&BT[(size_t)(colBase + row) * K + k0 + c8], &Bs[ch * 8]);
    }
    __syncthreads();

    short8 af[4], bfr[4];
#pragma unroll
    for (int i = 0; i < 4; ++i)
      af[i] = *(const short8*)&As[(qr * 64 + i * 16 + m16) * 32 + quad * 8];
#pragma unroll
    for (int j = 0; j < 4; ++j)
      bfr[j] = *(const short8*)&Bs[(qc * 64 + j * 16 + m16) * 32 + quad * 8];
#pragma unroll
    for (int i = 0; i < 4; ++i)
#pragma unroll
      for (int j = 0; j < 4; ++j)
        acc[i][j] = __builtin_amdgcn_mfma_f32_16x16x32_bf16(af[i], bfr[j], acc[i][j], 0, 0, 0);
  }

  float bv[4];
#pragma unroll
  for (int j = 0; j < 4; ++j)
    bv[j] = bias ? bias[colBase + qc * 64 + j * 16 + m16] : 0.f;

#pragma unroll
  for (int i = 0; i < 4; ++i) {
    int row0 = rowBase + qr * 64 + i * 16 + quad * 4;
#pragma unroll
    for (int j = 0; j < 4; ++j) {
      int col = colBase + qc * 64 + j * 16 + m16;
#pragma unroll
      for (int r = 0; r < 4; ++r) {
        float f = acc[i][j][r] + bv[j];
        if (F32OUT)
          ((float*)Cout)[(size_t)(row0 + r) * N + col] = f;
        else
          ((unsigned short*)Cout)[(size_t)(row0 + r) * N + col] = f2bf(f);
      }
    }
  }
}

// ---------------------------------------------------------------------------
// Co-residency GEMM for the big (M x 1024 x 1024) GEMMs.
// Tile 128(M) x 256(N), BK=32, 4 waves (1M x 4N), per-wave 128x64 output:
// 12 ds_read_b128 -> 32 MFMA per wave per K-tile (ratio 2.67).
// LDS = 2 x (A 8KB + B 16KB) = 48 KB dbuf -> 2 blocks/CU co-resident
// (VGPR ~200 caps at 2 waves/SIMD). Grid = 192x4 = 768 = 3 blocks/CU of
// work, balanced. Co-resident blocks at different phases overlap LDS-read
// bursts with MFMA bursts (m114/m97 mechanism) -- no lockstep pipeline.
// Per K-tile: ONE vmcnt(0) + ONE s_barrier; next tile's 6 GLD16 issued
// immediately AFTER the head barrier so they get a full tile (~1200 cy >
// 900 cy HBM) to land -> head drain ~free (fixes m97's exposed latency).
// Swizzle (BK=32, 4 chunks/row): key = (row>>1)&3 (NOT row&3: that leaves
// rows r,r+4,r+8,r+12 on identical banks = 4-way). With this key rows
// 0..7 hit 8 distinct (parity x chunk) slots; r vs r+8 = 2-way = free.
// Read side: chunk = quad ^ ((m16>>1)&3), lane-constant.
// Hazards: GLD16 of tile kt+1 (issued after head barrier of kt) writes
// buf[kt+1 & 1]; its previous reads (tile kt-1) retired before that
// barrier. ds_reads of kt gated by WAITV(0)+BARR at head of kt.
// Requires: M%128==0, N%256==0, K%32==0, grid%8==0.
// ---------------------------------------------------------------------------
template <bool F32OUT>
__global__ __launch_bounds__(256, 2) void gemm_bt128(
    const unsigned short* __restrict__ A, const unsigned short* __restrict__ BT,
    void* __restrict__ Cout, const float* __restrict__ bias,
    int M, int N, int K) {
  __shared__ __attribute__((aligned(16))) unsigned short As[2][128 * 32];
  __shared__ __attribute__((aligned(16))) unsigned short Bs[2][256 * 32];

  const int nbx = N >> 8;                       // 4
  int tid = (blockIdx.x & 7) * (gridDim.x >> 3) + (blockIdx.x >> 3);
  const int bx = tid % nbx, by = tid / nbx;
  const int rowBase = by * 128, colBase = bx * 256;

  const int t = threadIdx.x;                    // 256
  const int wave = t >> 6, lane = t & 63;       // wave = N-column of wave grid
  const int m16 = lane & 15, quad = lane >> 4;
  const int ck = quad ^ ((m16 >> 1) & 3);       // read-side swizzled chunk

  // Staging: A tile 128x4 chunks (512 -> 2/thread), B 256x4 (1024 -> 4/thread)
  const unsigned short* srcA[2]; int offA[2];
#pragma unroll
  for (int u = 0; u < 2; ++u) {
    int c = u * 256 + t;                        // linear chunk = row*4 + pch
    int row = c >> 2, pch = c & 3;
    int l = pch ^ ((row >> 1) & 3);             // logical k-chunk placed here
    srcA[u] = A + (size_t)(rowBase + row) * K + l * 8;
    offA[u] = c * 8;                            // shorts
  }
  const unsigned short* srcB[4]; int offB[4];
#pragma unroll
  for (int u = 0; u < 4; ++u) {
    int c = u * 256 + t;
    int row = c >> 2, pch = c & 3;              // row = B column index
    int l = pch ^ ((row >> 1) & 3);
    srcB[u] = BT + (size_t)(colBase + row) * K + l * 8;
    offB[u] = c * 8;
  }

  floatx4 acc[8][4];
#pragma unroll
  for (int i = 0; i < 8; ++i)
#pragma unroll
    for (int j = 0; j < 4; ++j) {
      acc[i][j][0] = 0.f; acc[i][j][1] = 0.f; acc[i][j][2] = 0.f; acc[i][j][3] = 0.f;
    }

#define WAITV0() asm volatile("s_waitcnt vmcnt(0)" ::: "memory")
#define BARR()   asm volatile("s_barrier" ::: "memory")

  // Prologue: stage tile 0 into buf 0.
#pragma unroll
  for (int u = 0; u < 2; ++u) GLD16(srcA[u], &As[0][offA[u]]);
#pragma unroll
  for (int u = 0; u < 4; ++u) GLD16(srcB[u], &Bs[0][offB[u]]);

  const int NT = K >> 5;                        // 32 K-tiles
  int cur = 0;
#pragma unroll 1
  for (int kt = 0; kt < NT; ++kt, cur ^= 1) {
    WAITV0(); BARR();                           // tile kt landed, all waves know
    if (kt + 1 < NT) {                          // prefetch kt+1 early (covers
      const int ko = (kt + 1) << 5;             // HBM latency under this tile)
      const int nxt = cur ^ 1;
#pragma unroll
      for (int u = 0; u < 2; ++u) GLD16(srcA[u] + ko, &As[nxt][offA[u]]);
#pragma unroll
      for (int u = 0; u < 4; ++u) GLD16(srcB[u] + ko, &Bs[nxt][offB[u]]);
    }
    short8 af[8], bfr[4];
#pragma unroll
    for (int i = 0; i < 8; ++i)
      af[i] = *(const short8*)&As[cur][(i * 16 + m16) * 32 + ck * 8];
#pragma unroll
    for (int j = 0; j < 4; ++j)
      bfr[j] = *(const short8*)&Bs[cur][(wave * 64 + j * 16 + m16) * 32 + ck * 8];
    __builtin_amdgcn_s_setprio(1);
#pragma unroll
    for (int i = 0; i < 8; ++i)
#pragma unroll
      for (int j = 0; j < 4; ++j)
        acc[i][j] = __builtin_amdgcn_mfma_f32_16x16x32_bf16(af[i], bfr[j], acc[i][j], 0, 0, 0);
    __builtin_amdgcn_s_setprio(0);
  }
#undef WAITV0
#undef BARR

  float bv[4];
#pragma unroll
  for (int jg = 0; jg < 4; ++jg)
    bv[jg] = bias ? bias[colBase + wave * 64 + jg * 16 + m16] : 0.f;

#pragma unroll
  for (int ig = 0; ig < 8; ++ig) {
    int row0 = rowBase + ig * 16 + quad * 4;
#pragma unroll
    for (int jg = 0; jg < 4; ++jg) {
      int col = colBase + wave * 64 + jg * 16 + m16;
#pragma unroll
      for (int r = 0; r < 4; ++r) {
        float f = acc[ig][jg][r] + bv[jg];
        if (F32OUT)
          ((float*)Cout)[(size_t)(row0 + r) * N + col] = f;
        else
          ((unsigned short*)Cout)[(size_t)(row0 + r) * N + col] = f2bf(f);
      }
    }
  }
}

// ---------------------------------------------------------------------------
// Per-(b,h) scores + softmax. qk (384 x 2048) fp32: [0,1024)=q, [1024,2048)=k.
// ---------------------------------------------------------------------------
__global__ __launch_bounds__(128) void softmax_k(
    const float* __restrict__ qk, unsigned short* __restrict__ attn) {
  int bh = blockIdx.x;
  int b = bh >> 4, h = bh & 15;
  __shared__ float ks[96][64];   // 24 KB
  __shared__ float sc[96][96];   // 36 KB, [m][t] layout
  int t = threadIdx.x;
  for (int idx = t; idx < 96 * 64; idx += 128) {
    int n = idx >> 6, d = idx & 63;
    ks[n][d] = qk[(size_t)(b * 96 + n) * 2048 + 1024 + h * 64 + d];
  }
  __syncthreads();
  if (t < 96) {
    float qreg[64];
    const float* qrow = qk + (size_t)(b * 96 + t) * 2048 + h * 64;
#pragma unroll
    for (int d = 0; d < 64; ++d) qreg[d] = qrow[d];

    float mx = -1e30f;
    for (int m = 0; m < 96; ++m) {
      float s0 = 0.f, s1 = 0.f, s2 = 0.f, s3 = 0.f;
#pragma unroll
      for (int d = 0; d < 64; d += 4) {
        s0 += qreg[d + 0] * ks[m][d + 0];
        s1 += qreg[d + 1] * ks[m][d + 1];
        s2 += qreg[d + 2] * ks[m][d + 2];
        s3 += qreg[d + 3] * ks[m][d + 3];
      }
      float s = ((s0 + s1) + (s2 + s3)) * 0.125f;  // hd^-0.5
      sc[m][t] = s;
      mx = fmaxf(mx, s);
    }
    float sum = 0.f;
    for (int m = 0; m < 96; ++m) {
      float e = __expf(sc[m][t] - mx);
      sc[m][t] = e;
      sum += e;
    }
    float inv = 1.0f / sum;
    size_t base = (size_t)(bh * 96 + t) * 96;
    for (int m = 0; m < 96; ++m) attn[base + m] = f2bf(sc[m][t] * inv);
  }
}

// ---------------------------------------------------------------------------
// MFMA attn-apply (no LDS). Per (b,h): out2'(96 x 4096) = attn_bh(96x96) @
// V'_bh(96x4096), where V'[m][p*64+d] = V[((b*96+m)*64+p)*1024 + h*64+d].
// ---------------------------------------------------------------------------
__global__ __launch_bounds__(256) void attn_apply_mfma(
    const unsigned short* __restrict__ attn, const unsigned short* __restrict__ V,
    unsigned short* __restrict__ out2) {
  const int bid = blockIdx.x;
  const int bh = bid >> 5, ct = bid & 31;
  const int b = bh >> 4;           // 0 when launched per-batch with grid 512
  const int t = threadIdx.x;
  const int wave = t >> 6, lane = t & 63;
  const int m16 = lane & 15, quad = lane >> 4;

  const unsigned short* An = attn + (size_t)bh * 96 * 96;   // attn[bh][n][m]
  const int vb = b * 96 * 64 * CC;                           // batch offset in V

  floatx4 acc[6][2];
#pragma unroll
  for (int i = 0; i < 6; ++i)
#pragma unroll
    for (int j = 0; j < 2; ++j) {
      acc[i][j][0] = 0.f; acc[i][j][1] = 0.f; acc[i][j][2] = 0.f; acc[i][j][3] = 0.f;
    }

  int p_[2], base_[2];
#pragma unroll
  for (int jj = 0; jj < 2; ++jj) {
    int colL = wave * 32 + jj * 16;              // 0..112, multiple of 16
    int p = ct * 2 + (colL >> 6);
    int d = (colL & 63) + m16;
    p_[jj] = p;
    base_[jj] = vb + p * CC + ((bh & 15) * 64) + d;   // + m*64*CC per k
  }

#pragma unroll
  for (int k0 = 0; k0 < 96; k0 += 32) {
    short8 af[6];
#pragma unroll
    for (int i = 0; i < 6; ++i)
      af[i] = *(const short8*)&An[(i * 16 + m16) * 96 + k0 + quad * 8];
#pragma unroll
    for (int jj = 0; jj < 2; ++jj) {
      short8 bfr;
#pragma unroll
      for (int j = 0; j < 8; ++j)
        bfr[j] = (short)V[(size_t)base_[jj] + (size_t)(k0 + quad * 8 + j) * (64 * CC)];
#pragma unroll
      for (int i = 0; i < 6; ++i)
        acc[i][jj] = __builtin_amdgcn_mfma_f32_16x16x32_bf16(af[i], bfr, acc[i][jj], 0, 0, 0);
    }
  }

#pragma unroll
  for (int jj = 0; jj < 2; ++jj) {
    int colL = wave * 32 + jj * 16;
    int d = (colL & 63) + m16;
    size_t obase = (size_t)(b * 96) * 64 * CC + (size_t)p_[jj] * CC + (bh & 15) * 64 + d;
#pragma unroll
    for (int i = 0; i < 6; ++i) {
#pragma unroll
      for (int r = 0; r < 4; ++r) {
        int n = i * 16 + quad * 4 + r;
        out2[obase + (size_t)n * (64 * CC)] = f2bf(acc[i][jj][r]);
      }
    }
  }
}

// ---------------------------------------------------------------------------
// Buffer plan identical to previous rounds (see chunked-ordering proof).
// ---------------------------------------------------------------------------
extern "C" void kernel_launch(void* const* d_in, const int* in_sizes, int n_in,
                              void* d_out, int out_size, void* d_ws, size_t ws_size,
                              hipStream_t stream) {
  const float* x      = (const float*)d_in[0];  // (4,96,64,1024) fp32
  const float* W_qkv  = (const float*)d_in[1];  // (1024,3072) fp32
  const float* W_proj = (const float*)d_in[2];  // (1024,1024) fp32
  const float* b_proj = (const float*)d_in[3];  // (1024,) fp32
  float* out = (float*)d_out;                   // (4,96,64,1024) fp32

  char* w = (char*)d_ws;
  unsigned short* WqkvT = (unsigned short*)(w);                    // 6 MB
  unsigned short* WpT   = (unsigned short*)(w + 6291456);          // 2 MB
  unsigned short* xm    = (unsigned short*)(w + 8388608);          // 0.75 MB
  float*          qkbuf = (float*)(w + 9175040);                   // 3 MB
  unsigned short* attn  = (unsigned short*)(w + 12320768);         // 1.125 MB
  unsigned short* out2w = (unsigned short*)(w + 13500416);         // 48 or 12 MB
  unsigned short* xbf   = (unsigned short*)d_out;                      // 48 MB
  unsigned short* Vbuf  = (unsigned short*)((char*)d_out + 50331648);  // 48 MB

  const bool fullws = ws_size >= (size_t)13500416 + 50331648;

  // 1) fused convert(x->bf16) + mean-pool over P (q/k only need the mean)
  conv_mean<<<dim3(384), 256, 0, stream>>>(x, xbf, xm);

  // 2) weight convert+transpose (B^T bf16 layout)
  transpose_f32_bf16<<<dim3(96, 32), 256, 0, stream>>>(W_qkv, WqkvT, 1024, 3072, 3072);
  transpose_f32_bf16<<<dim3(32, 32), 256, 0, stream>>>(W_proj, WpT, 1024, 1024, 1024);

  // 3) qk = xm @ W_qkv[:, :2048] -> fp32 (small; plain mapping)
  gemm_bt<true, false><<<dim3(48), 256, 0, stream>>>(
      xm, WqkvT, qkbuf, nullptr, 384, 2048, 1024, 16);

  // 4) scores + softmax -> attn bf16
  softmax_k<<<dim3(64), 128, 0, stream>>>(qkbuf, attn);

  // 5) V = xbf @ W_qkv[:, 2048:3072] -> bf16 (128x256 co-residency GEMM)
  gemm_bt128<false><<<dim3(768), 256, 0, stream>>>(
      xbf, WqkvT + (size_t)2048 * 1024, Vbuf, nullptr, 24576, 1024, 1024);

  if (fullws) {
    // 6) attn-mix, all batches in one launch (64 bh x 32 col-tiles)
    attn_apply_mfma<<<dim3(2048), 256, 0, stream>>>(attn, Vbuf, out2w);
    // 7) out = out2 @ W_proj + b_proj -> fp32, one full-M launch
    gemm_bt128<true><<<dim3(768), 256, 0, stream>>>(
        out2w, WpT, out, b_proj, 24576, 1024, 1024);
  } else {
    for (int b = 0; b < 4; ++b) {
      attn_apply_mfma<<<dim3(512), 256, 0, stream>>>(
          attn + (size_t)b * 16 * 96 * 96,
          Vbuf + (size_t)b * 6144 * 1024,
          out2w);
      gemm_bt128<true><<<dim3(192), 256, 0, stream>>>(
          out2w, WpT, out + (size_t)b * 6144 * 1024, b_proj, 6144, 1024, 1024);
    }
  }
}

// Round 6
// 387.020 us; speedup vs baseline: 1.0809x; 1.0809x over previous
//
#include <hip/hip_runtime.h>
#include <cstdint>
#include <cstddef>

// VarAttention: B=4, N=96, P=64, C=1024, H=16, hd=64. tokens = 24576.
// Buffers are FP32 (reference dtype). Internal compute: bf16 MFMA, fp32 accum.
#define PPP  64
#define CC   1024

typedef __attribute__((ext_vector_type(8))) short short8;
typedef __attribute__((ext_vector_type(4))) float floatx4;
typedef __attribute__((ext_vector_type(4))) unsigned short ushort4v;

__device__ inline float bf2f(unsigned short u) {
  union { unsigned int i; float f; } v; v.i = ((unsigned int)u) << 16; return v.f;
}
__device__ inline unsigned short f2bf(float f) {
  union { float f; unsigned int i; } v; v.f = f;
  unsigned int x = v.i;
  unsigned int r = (x + 0x7fffu + ((x >> 16) & 1u)) >> 16;  // RNE
  return (unsigned short)r;
}

// global->LDS direct DMA, 16B/lane; LDS dest = wave-uniform base + lane*16.
#define GLD16(gp, lp)                                                          \
  __builtin_amdgcn_global_load_lds(                                            \
      (const __attribute__((address_space(1))) void*)(gp),                     \
      (__attribute__((address_space(3))) void*)(lp), 16, 0, 0)

// ---------------------------------------------------------------------------
// Fused convert + mean-pool: one pass over x (96 MB fp32).
// ---------------------------------------------------------------------------
__global__ __launch_bounds__(256) void conv_mean(
    const float* __restrict__ x, unsigned short* __restrict__ xbf,
    unsigned short* __restrict__ xm) {
  int bn = blockIdx.x;
  int c4 = threadIdx.x * 4;
  const float* xp = x + (size_t)bn * (PPP * CC) + c4;
  unsigned short* xo = xbf + (size_t)bn * (PPP * CC) + c4;
  float4 s = {0.f, 0.f, 0.f, 0.f};
#pragma unroll 8
  for (int p = 0; p < PPP; ++p) {
    float4 v = *(const float4*)&xp[(size_t)p * CC];
    s.x += v.x; s.y += v.y; s.z += v.z; s.w += v.w;
    ushort4v pk;
    pk.x = f2bf(v.x); pk.y = f2bf(v.y); pk.z = f2bf(v.z); pk.w = f2bf(v.w);
    *(ushort4v*)&xo[(size_t)p * CC] = pk;
  }
  ushort4v pm;
  pm.x = f2bf(s.x * (1.0f / PPP)); pm.y = f2bf(s.y * (1.0f / PPP));
  pm.z = f2bf(s.z * (1.0f / PPP)); pm.w = f2bf(s.w * (1.0f / PPP));
  *(ushort4v*)&xm[(size_t)bn * CC + c4] = pm;
}

// ---------------------------------------------------------------------------
// Convert+transpose: dst_bf16[c][r] = src_f32[r][c]. Grid (Cc/32, R/32), 256.
// ---------------------------------------------------------------------------
__global__ __launch_bounds__(256) void transpose_f32_bf16(
    const float* __restrict__ src, unsigned short* __restrict__ dst,
    int R, int Cc, int src_stride) {
  __shared__ unsigned short tile[32][33];
  int tc = blockIdx.x * 32, tr = blockIdx.y * 32;
  int tx = threadIdx.x & 31, ty = threadIdx.x >> 5;  // 32 x 8
  for (int yy = ty; yy < 32; yy += 8)
    tile[yy][tx] = f2bf(src[(size_t)(tr + yy) * src_stride + tc + tx]);
  __syncthreads();
  for (int yy = ty; yy < 32; yy += 8)
    dst[(size_t)(tc + yy) * R + tr + tx] = tile[tx][yy];
}

// ---------------------------------------------------------------------------
// Small-M MFMA GEMM (m97 structure) kept for the qk projection only.
// ---------------------------------------------------------------------------
template <bool F32OUT, bool SWIZ>
__global__ __launch_bounds__(256) void gemm_bt(
    const unsigned short* __restrict__ A, const unsigned short* __restrict__ BT,
    void* __restrict__ Cout, const float* __restrict__ bias,
    int M, int N, int K, int nbx) {
  __shared__ unsigned short As[128 * 32];
  __shared__ unsigned short Bs[128 * 32];

  int bx, by;
  {
    int bid = blockIdx.x;
    if (SWIZ) {
      bx = (bid >> 3) & 7;
      by = (bid & 7) * (gridDim.x >> 6) + (bid >> 6);
    } else {
      bx = bid % nbx;
      by = bid / nbx;
    }
  }
  const int rowBase = by * 128;
  const int colBase = bx * 128;
  const int t = threadIdx.x;
  const int wave = t >> 6, lane = t & 63;
  const int qr = wave >> 1, qc = wave & 1;
  const int m16 = lane & 15, quad = lane >> 4;

  floatx4 acc[4][4];
#pragma unroll
  for (int i = 0; i < 4; ++i)
#pragma unroll
    for (int j = 0; j < 4; ++j) {
      acc[i][j][0] = 0.f; acc[i][j][1] = 0.f; acc[i][j][2] = 0.f; acc[i][j][3] = 0.f;
    }

  for (int k0 = 0; k0 < K; k0 += 32) {
    __syncthreads();
#pragma unroll
    for (int u = 0; u < 2; ++u) {
      int ch = (u * 4 + wave) * 64 + lane;      // 0..511
      int row = ch >> 2, c8 = (ch & 3) << 3;    // 16B chunks of a 32-wide k-row
      GLD16(&A [(size_t)(rowBase + row) * K + k0 + c8], &As[ch * 8]);
      GLD16(&BT[(size_t)(colBase + row) * K + k0 + c8], &Bs[ch * 8]);
    }
    __syncthreads();

    short8 af[4], bfr[4];
#pragma unroll
    for (int i = 0; i < 4; ++i)
      af[i] = *(const short8*)&As[(qr * 64 + i * 16 + m16) * 32 + quad * 8];
#pragma unroll
    for (int j = 0; j < 4; ++j)
      bfr[j] = *(const short8*)&Bs[(qc * 64 + j * 16 + m16) * 32 + quad * 8];
#pragma unroll
    for (int i = 0; i < 4; ++i)
#pragma unroll
      for (int j = 0; j < 4; ++j)
        acc[i][j] = __builtin_amdgcn_mfma_f32_16x16x32_bf16(af[i], bfr[j], acc[i][j], 0, 0, 0);
  }

  float bv[4];
#pragma unroll
  for (int j = 0; j < 4; ++j)
    bv[j] = bias ? bias[colBase + qc * 64 + j * 16 + m16] : 0.f;

#pragma unroll
  for (int i = 0; i < 4; ++i) {
    int row0 = rowBase + qr * 64 + i * 16 + quad * 4;
#pragma unroll
    for (int j = 0; j < 4; ++j) {
      int col = colBase + qc * 64 + j * 16 + m16;
#pragma unroll
      for (int r = 0; r < 4; ++r) {
        float f = acc[i][j][r] + bv[j];
        if (F32OUT)
          ((float*)Cout)[(size_t)(row0 + r) * N + col] = f;
        else
          ((unsigned short*)Cout)[(size_t)(row0 + r) * N + col] = f2bf(f);
      }
    }
  }
}

// ---------------------------------------------------------------------------
// Pipelined MFMA GEMM for the big (M x 1024 x 1024) GEMMs.  [R3 version —
// measured best 65 us.]  Tile 256x256, BK=64, 8 waves (2M x 4N), per-wave
// 128x64, each fragment read from LDS exactly once per K-tile.
// ONE counted vmcnt + ONE s_barrier per K-tile; A double-buffer (2x32KB) +
// B TRIPLE-buffer (3x32KB) = 160 KiB; A of kt+1 and B of kt+2 staged during
// kt; at tile head s_waitcnt vmcnt(4) confirms the whole tile. Swizzle:
// 16B-chunk ^= (row&7), pre-swizzled global source + swizzled ds_read.
// Requires: M%256==0, N%256==0, K%64==0, K>=128, grid%8==0.
// ---------------------------------------------------------------------------
template <bool F32OUT>
__global__ __launch_bounds__(512, 2) void gemm_bt256(
    const unsigned short* __restrict__ A, const unsigned short* __restrict__ BT,
    void* __restrict__ Cout, const float* __restrict__ bias,
    int M, int N, int K) {
  __shared__ __attribute__((aligned(16))) unsigned short As[2][256 * 64];
  __shared__ __attribute__((aligned(16))) unsigned short Bs[3][256 * 64];

  const int nbx = N >> 8;
  int tid = (blockIdx.x & 7) * (gridDim.x >> 3) + (blockIdx.x >> 3);
  const int bx = tid % nbx, by = tid / nbx;
  const int rowBase = by * 256, colBase = bx * 256;

  const int t = threadIdx.x;          // 512
  const int wave = t >> 6, lane = t & 63;
  const int wr = wave >> 2, wc = wave & 3;   // 2M x 4N wave grid
  const int m16 = lane & 15, quad = lane >> 4;
  const int sw7 = m16 & 7;                   // read-side swizzle key (= row&7)

  const unsigned short* srcA[4];
  int offA[4];
#pragma unroll
  for (int u = 0; u < 4; ++u) {
    int c = u * 512 + t;                     // chunk = row*8 + physchunk
    int row = c >> 3, pch = c & 7;
    int l = pch ^ (row & 7);                 // logical chunk placed here
    srcA[u] = A + (size_t)(rowBase + row) * K + l * 8;
    offA[u] = c * 8;                         // shorts
  }
  const unsigned short* srcB[2][2];
  int offB[2][2];
#pragma unroll
  for (int g = 0; g < 2; ++g)
#pragma unroll
    for (int u = 0; u < 2; ++u) {
      int i = u * 512 + t;
      int col = g * 32 + ((i >> 8) << 6) + ((i >> 3) & 31);
      int kcp = i & 7;
      int l = kcp ^ (col & 7);
      srcB[g][u] = BT + (size_t)(colBase + col) * K + l * 8;
      offB[g][u] = col * 64 + kcp * 8;       // shorts
    }

  floatx4 acc[8][4];
#pragma unroll
  for (int i = 0; i < 8; ++i)
#pragma unroll
    for (int j = 0; j < 4; ++j) {
      acc[i][j][0] = 0.f; acc[i][j][1] = 0.f; acc[i][j][2] = 0.f; acc[i][j][3] = 0.f;
    }

  short8 ar[4][2];        // A frags of current qa: [i][kh]
  short8 br[2][2][2];     // B frags, both halves live: [qb][j][kh]

#define RD_A(buf, qa)                                                          \
  _Pragma("unroll") for (int i_ = 0; i_ < 4; ++i_)                             \
  _Pragma("unroll") for (int kh_ = 0; kh_ < 2; ++kh_)                          \
    ar[i_][kh_] = *(const short8*)&As[buf][                                    \
        (wr * 128 + (qa) * 64 + i_ * 16 + m16) * 64 +                          \
        (((kh_ * 4 + quad) ^ sw7) * 8)];
#define RD_B(buf, qb)                                                          \
  _Pragma("unroll") for (int j_ = 0; j_ < 2; ++j_)                             \
  _Pragma("unroll") for (int kh_ = 0; kh_ < 2; ++kh_)                          \
    br[qb][j_][kh_] = *(const short8*)&Bs[buf][                                \
        (wc * 64 + (qb) * 32 + j_ * 16 + m16) * 64 +                           \
        (((kh_ * 4 + quad) ^ sw7) * 8)];
#define MFMA_PH(qa, qb)                                                        \
  __builtin_amdgcn_s_setprio(1);                                               \
  _Pragma("unroll") for (int kh_ = 0; kh_ < 2; ++kh_)                          \
  _Pragma("unroll") for (int i_ = 0; i_ < 4; ++i_)                             \
  _Pragma("unroll") for (int j_ = 0; j_ < 2; ++j_)                             \
    acc[(qa) * 4 + i_][(qb) * 2 + j_] =                                        \
        __builtin_amdgcn_mfma_f32_16x16x32_bf16(                               \
            ar[i_][kh_], br[qb][j_][kh_], acc[(qa) * 4 + i_][(qb) * 2 + j_],   \
            0, 0, 0);                                                          \
  __builtin_amdgcn_s_setprio(0);
#define WAITV(n) asm volatile("s_waitcnt vmcnt(" #n ")" ::: "memory")
#define BARR() asm volatile("s_barrier" ::: "memory")
#define FEN() asm volatile("" ::: "memory")

  // Prologue, order pinned (steady-state-consistent ages):
  GLD16(srcB[0][0], &Bs[0][offB[0][0]]);
  GLD16(srcB[0][1], &Bs[0][offB[0][1]]); FEN();
  GLD16(srcB[1][0], &Bs[0][offB[1][0]]);
  GLD16(srcB[1][1], &Bs[0][offB[1][1]]); FEN();
  GLD16(srcA[0], &As[0][offA[0]]);
  GLD16(srcA[2], &As[0][offA[2]]); FEN();
  GLD16(srcA[1], &As[0][offA[1]]);
  GLD16(srcA[3], &As[0][offA[3]]); FEN();
  GLD16(srcB[0][0] + 64, &Bs[1][offB[0][0]]);
  GLD16(srcB[0][1] + 64, &Bs[1][offB[0][1]]); FEN();
  GLD16(srcB[1][0] + 64, &Bs[1][offB[1][0]]);
  GLD16(srcB[1][1] + 64, &Bs[1][offB[1][1]]); FEN();

  const int NT = K >> 6;
  int acur = 0, bcur = 0;
#pragma unroll 1
  for (int kt = 0; kt < NT - 1; ++kt) {
    const int anxt = acur ^ 1;
    const int bnx2 = (bcur >= 1) ? bcur - 1 : 2;   // (bcur+2)%3
    const int koA = (kt + 1) << 6;                 // shorts into K
    const int koB = (kt + 2) << 6;
    const bool doB = (kt + 2) < NT;
    WAITV(4); BARR();
    RD_A(acur, 0);                         // 8 reads -> ar (qa=0)
    RD_B(bcur, 0);                         // 4 -> br[0]
    RD_B(bcur, 1);                         // 4 -> br[1]
    GLD16(srcA[0] + koA, &As[anxt][offA[0]]);
    GLD16(srcA[2] + koA, &As[anxt][offA[2]]); FEN();
    MFMA_PH(0, 0);
    GLD16(srcA[1] + koA, &As[anxt][offA[1]]);
    GLD16(srcA[3] + koA, &As[anxt][offA[3]]); FEN();
    MFMA_PH(0, 1);
    RD_A(acur, 1);                         // 8 -> ar overwrite (qa=1)
    if (doB) {
      GLD16(srcB[0][0] + koB, &Bs[bnx2][offB[0][0]]);
      GLD16(srcB[0][1] + koB, &Bs[bnx2][offB[0][1]]);
    }
    FEN();
    MFMA_PH(1, 0);
    if (doB) {
      GLD16(srcB[1][0] + koB, &Bs[bnx2][offB[1][0]]);
      GLD16(srcB[1][1] + koB, &Bs[bnx2][offB[1][1]]);
    }
    FEN();
    MFMA_PH(1, 1);
    acur = anxt; bcur = (bcur == 2) ? 0 : bcur + 1;
  }
  WAITV(0); BARR();
  RD_A(acur, 0); RD_B(bcur, 0); RD_B(bcur, 1);
  MFMA_PH(0, 0);
  MFMA_PH(0, 1);
  RD_A(acur, 1);
  MFMA_PH(1, 0);
  MFMA_PH(1, 1);

#undef RD_A
#undef RD_B
#undef MFMA_PH
#undef WAITV
#undef BARR
#undef FEN

  float bv[4];
#pragma unroll
  for (int jg = 0; jg < 4; ++jg)
    bv[jg] = bias ? bias[colBase + wc * 64 + jg * 16 + m16] : 0.f;

#pragma unroll
  for (int ig = 0; ig < 8; ++ig) {
    int row0 = rowBase + wr * 128 + ig * 16 + quad * 4;
#pragma unroll
    for (int jg = 0; jg < 4; ++jg) {
      int col = colBase + wc * 64 + jg * 16 + m16;
#pragma unroll
      for (int r = 0; r < 4; ++r) {
        float f = acc[ig][jg][r] + bv[jg];
        if (F32OUT)
          ((float*)Cout)[(size_t)(row0 + r) * N + col] = f;
        else
          ((unsigned short*)Cout)[(size_t)(row0 + r) * N + col] = f2bf(f);
      }
    }
  }
}

// ---------------------------------------------------------------------------
// Per-(b,h) scores + softmax. qk (384 x 2048) fp32: [0,1024)=q, [1024,2048)=k.
// ---------------------------------------------------------------------------
__global__ __launch_bounds__(128) void softmax_k(
    const float* __restrict__ qk, unsigned short* __restrict__ attn) {
  int bh = blockIdx.x;
  int b = bh >> 4, h = bh & 15;
  __shared__ float ks[96][64];   // 24 KB
  __shared__ float sc[96][96];   // 36 KB, [m][t] layout
  int t = threadIdx.x;
  for (int idx = t; idx < 96 * 64; idx += 128) {
    int n = idx >> 6, d = idx & 63;
    ks[n][d] = qk[(size_t)(b * 96 + n) * 2048 + 1024 + h * 64 + d];
  }
  __syncthreads();
  if (t < 96) {
    float qreg[64];
    const float* qrow = qk + (size_t)(b * 96 + t) * 2048 + h * 64;
#pragma unroll
    for (int d = 0; d < 64; ++d) qreg[d] = qrow[d];

    float mx = -1e30f;
    for (int m = 0; m < 96; ++m) {
      float s0 = 0.f, s1 = 0.f, s2 = 0.f, s3 = 0.f;
#pragma unroll
      for (int d = 0; d < 64; d += 4) {
        s0 += qreg[d + 0] * ks[m][d + 0];
        s1 += qreg[d + 1] * ks[m][d + 1];
        s2 += qreg[d + 2] * ks[m][d + 2];
        s3 += qreg[d + 3] * ks[m][d + 3];
      }
      float s = ((s0 + s1) + (s2 + s3)) * 0.125f;  // hd^-0.5
      sc[m][t] = s;
      mx = fmaxf(mx, s);
    }
    float sum = 0.f;
    for (int m = 0; m < 96; ++m) {
      float e = __expf(sc[m][t] - mx);
      sc[m][t] = e;
      sum += e;
    }
    float inv = 1.0f / sum;
    size_t base = (size_t)(bh * 96 + t) * 96;
    for (int m = 0; m < 96; ++m) attn[base + m] = f2bf(sc[m][t] * inv);
  }
}

// ---------------------------------------------------------------------------
// MFMA attn-apply, LDS-staged V (NEW).  Per block (bh, ct): stage V' tile
// Vt[m=0..95][e=0..127] (e = (p-2ct)*64 + d) into 24 KB LDS via 6 coalesced
// GLD16/thread (16B contiguous in global: d-consecutive).  16B-chunk XOR
// swizzle key=(m>>3)&3 (pre-swizzled SOURCE + swizzled READ, rule 21):
// derived banks: 4 quads -> 4 distinct chunk-columns, residual 2-way = free.
// B-fragments built from LDS u16 reads (~3cy) instead of 25M scalar 2B
// global loads at 128KB stride (the old version's issue/latency bound).
// P fragments live in registers, loaded straight from L2-hot global.
// Indices/output layout identical to the previous (passing) version.
// ---------------------------------------------------------------------------
__global__ __launch_bounds__(256, 2) void attn_apply_mfma(
    const unsigned short* __restrict__ attn, const unsigned short* __restrict__ V,
    unsigned short* __restrict__ out2) {
  __shared__ __attribute__((aligned(16))) unsigned short Vt[96 * 128];  // 24 KB
  const int bid = blockIdx.x;
  const int bh = bid >> 5, ct = bid & 31;
  const int b = bh >> 4, h = bh & 15;   // b=0 when launched per-batch
  const int t = threadIdx.x;
  const int w = t >> 6, lane = t & 63;
  const int m16 = lane & 15, quad = lane >> 4;
  const int p0 = ct * 2;

  // ---- stage V tile (1536 16B chunks, 6/thread). Element e of row m lives
  // at LDS short-offset m*128 + ((e>>3)^key(m))*8 + (e&7), key=(m>>3)&3.
#pragma unroll
  for (int u = 0; u < 6; ++u) {
    int c = u * 256 + t;                 // 0..1535 = m*16 + physchunk
    int m = c >> 4, pch = c & 15;
    int l = pch ^ ((m >> 3) & 3);        // logical e-chunk placed here
    const unsigned short* src =
        V + (size_t)((b * 96 + m) * 64 + p0 + (l >> 3)) * CC + h * 64 + (l & 7) * 8;
    GLD16(src, &Vt[c * 8]);
  }

  // ---- P fragments (A-operand), registers. a[i][kc]: rows i*16+m16,
  // k = kc*32 + quad*8 + j. L2-hot (18 KB per bh, reused by 32 blocks).
  const unsigned short* An = attn + (size_t)bh * 96 * 96;
  short8 a[6][3];
#pragma unroll
  for (int i = 0; i < 6; ++i)
#pragma unroll
    for (int kc = 0; kc < 3; ++kc)
      a[i][kc] = *(const short8*)&An[(i * 16 + m16) * 96 + kc * 32 + quad * 8];

  floatx4 acc[6][2];
#pragma unroll
  for (int i = 0; i < 6; ++i)
#pragma unroll
    for (int jj = 0; jj < 2; ++jj) {
      acc[i][jj][0] = 0.f; acc[i][jj][1] = 0.f;
      acc[i][jj][2] = 0.f; acc[i][jj][3] = 0.f;
    }

  asm volatile("s_waitcnt vmcnt(0)" ::: "memory");
  __syncthreads();

  // ---- C(96x128) = P(96x96) @ Vt(96x128); wave w owns cols w*32..+31.
#pragma unroll
  for (int kc = 0; kc < 3; ++kc) {
    short8 bf[2];
#pragma unroll
    for (int jj = 0; jj < 2; ++jj) {
      const int col = w * 32 + jj * 16 + m16;
#pragma unroll
      for (int jx = 0; jx < 8; ++jx) {
        const int m = kc * 32 + quad * 8 + jx;
        bf[jj][jx] = (short)Vt[m * 128 + (((col >> 3) ^ ((m >> 3) & 3)) << 3) + (col & 7)];
      }
    }
    __builtin_amdgcn_s_setprio(1);
#pragma unroll
    for (int i = 0; i < 6; ++i)
#pragma unroll
      for (int jj = 0; jj < 2; ++jj)
        acc[i][jj] = __builtin_amdgcn_mfma_f32_16x16x32_bf16(a[i][kc], bf[jj], acc[i][jj], 0, 0, 0);
    __builtin_amdgcn_s_setprio(0);
  }

  // ---- write out (unchanged layout: out2 is (b,n,p,c) token-major)
#pragma unroll
  for (int jj = 0; jj < 2; ++jj) {
    const int colL = w * 32 + jj * 16;
    const int p = p0 + (colL >> 6);
    const int d = (colL & 63) + m16;
    size_t obase = (size_t)(b * 96) * 64 * CC + (size_t)p * CC + h * 64 + d;
#pragma unroll
    for (int i = 0; i < 6; ++i) {
#pragma unroll
      for (int r = 0; r < 4; ++r) {
        int n = i * 16 + quad * 4 + r;
        out2[obase + (size_t)n * (64 * CC)] = f2bf(acc[i][jj][r]);
      }
    }
  }
}

// ---------------------------------------------------------------------------
// Buffer plan identical to previous rounds (see chunked-ordering proof).
// ---------------------------------------------------------------------------
extern "C" void kernel_launch(void* const* d_in, const int* in_sizes, int n_in,
                              void* d_out, int out_size, void* d_ws, size_t ws_size,
                              hipStream_t stream) {
  const float* x      = (const float*)d_in[0];  // (4,96,64,1024) fp32
  const float* W_qkv  = (const float*)d_in[1];  // (1024,3072) fp32
  const float* W_proj = (const float*)d_in[2];  // (1024,1024) fp32
  const float* b_proj = (const float*)d_in[3];  // (1024,) fp32
  float* out = (float*)d_out;                   // (4,96,64,1024) fp32

  char* w = (char*)d_ws;
  unsigned short* WqkvT = (unsigned short*)(w);                    // 6 MB
  unsigned short* WpT   = (unsigned short*)(w + 6291456);          // 2 MB
  unsigned short* xm    = (unsigned short*)(w + 8388608);          // 0.75 MB
  float*          qkbuf = (float*)(w + 9175040);                   // 3 MB
  unsigned short* attn  = (unsigned short*)(w + 12320768);         // 1.125 MB
  unsigned short* out2w = (unsigned short*)(w + 13500416);         // 48 or 12 MB
  unsigned short* xbf   = (unsigned short*)d_out;                      // 48 MB
  unsigned short* Vbuf  = (unsigned short*)((char*)d_out + 50331648);  // 48 MB

  const bool fullws = ws_size >= (size_t)13500416 + 50331648;

  // 1) fused convert(x->bf16) + mean-pool over P (q/k only need the mean)
  conv_mean<<<dim3(384), 256, 0, stream>>>(x, xbf, xm);

  // 2) weight convert+transpose (B^T bf16 layout)
  transpose_f32_bf16<<<dim3(96, 32), 256, 0, stream>>>(W_qkv, WqkvT, 1024, 3072, 3072);
  transpose_f32_bf16<<<dim3(32, 32), 256, 0, stream>>>(W_proj, WpT, 1024, 1024, 1024);

  // 3) qk = xm @ W_qkv[:, :2048] -> fp32 (small; plain mapping)
  gemm_bt<true, false><<<dim3(48), 256, 0, stream>>>(
      xm, WqkvT, qkbuf, nullptr, 384, 2048, 1024, 16);

  // 4) scores + softmax -> attn bf16
  softmax_k<<<dim3(64), 128, 0, stream>>>(qkbuf, attn);

  // 5) V = xbf @ W_qkv[:, 2048:3072] -> bf16 (256x256 pipelined GEMM, R3)
  gemm_bt256<false><<<dim3(384), 512, 0, stream>>>(
      xbf, WqkvT + (size_t)2048 * 1024, Vbuf, nullptr, 24576, 1024, 1024);

  if (fullws) {
    // 6) attn-mix, all batches in one launch (64 bh x 32 col-tiles)
    attn_apply_mfma<<<dim3(2048), 256, 0, stream>>>(attn, Vbuf, out2w);
    // 7) out = out2 @ W_proj + b_proj -> fp32, one full-M launch
    gemm_bt256<true><<<dim3(384), 512, 0, stream>>>(
        out2w, WpT, out, b_proj, 24576, 1024, 1024);
  } else {
    for (int b = 0; b < 4; ++b) {
      attn_apply_mfma<<<dim3(512), 256, 0, stream>>>(
          attn + (size_t)b * 16 * 96 * 96,
          Vbuf + (size_t)b * 6144 * 1024,
          out2w);
      gemm_bt256<true><<<dim3(96), 512, 0, stream>>>(
          out2w, WpT, out + (size_t)b * 6144 * 1024, b_proj, 6144, 1024, 1024);
    }
  }
}